// Round 3
// baseline (17696.988 us; speedup 1.0000x reference)
//
#include <hip/hip_runtime.h>

#define GD 256   // grid (workgroups) -- must be <= CU count for residency
#define BD 256   // block

constexpr int TSTEPS = 256; // sequence length
constexpr int DD = 512;     // d_in = d_out = d_ctx = a_hid
constexpr int KK4 = 2048;   // 4*D_OUT
constexpr int LC = 128;     // context length

// ---- workspace layout (float offsets) ----
constexpr size_t OFF_HATT  = 0;                     // [32][512] row-major (coherent)
constexpr size_t OFF_BAR   = OFF_HATT + 16384;      // barrier ints
constexpr size_t OFF_ATT   = OFF_BAR  + 64;         // [32*128][512] context@Wc + b_att (WG-local)
constexpr size_t OFF_WCTXR = OFF_ATT  + 2097152;    // ring: [256][32][512] (atomics -> MALL)
constexpr size_t OFF_ZR    = OFF_WCTXR + 4194304;   // ring: [256][64]
constexpr size_t WS_FLOATS = OFF_ZR   + 16384;      // ~25.3 MB total

__device__ __forceinline__ float rcp_fast(float x) { return __builtin_amdgcn_rcpf(x); }
__device__ __forceinline__ float ftanh(float x) {
  float e = __expf(2.0f * x);
  return 1.0f - 2.0f * rcp_fast(e + 1.0f);
}
__device__ __forceinline__ float fsig(float x) { return rcp_fast(1.0f + __expf(-x)); }

// coherent (agent-scope, L2-bypassing) scalar access -- does NOT invalidate L2
__device__ __forceinline__ float cload(const float* p) {
  return __hip_atomic_load(p, __ATOMIC_RELAXED, __HIP_MEMORY_SCOPE_AGENT);
}
__device__ __forceinline__ void cstore(float* p, float v) {
  __hip_atomic_store(p, v, __ATOMIC_RELAXED, __HIP_MEMORY_SCOPE_AGENT);
}

// grid barrier: __syncthreads drains each wave's vmcnt (cross-WG stores are
// sc-coherent and land at MALL); relaxed agent add + spin; NO cache invalidation.
__device__ __forceinline__ void gsync(int* bar, int& gen) {
  __syncthreads();
  if (threadIdx.x == 0) {
    gen++;
    __hip_atomic_fetch_add(bar, 1, __ATOMIC_RELAXED, __HIP_MEMORY_SCOPE_AGENT);
    const int target = gen * GD;
    while (__hip_atomic_load(bar, __ATOMIC_RELAXED, __HIP_MEMORY_SCOPE_AGENT) < target)
      __builtin_amdgcn_s_sleep(2);
    asm volatile("" ::: "memory");
  }
  __syncthreads();
}

// Stage 32 rows x 512 cols (row stride rstride) into LDS transposed + XOR-swizzled,
// NORMAL cached loads. (k,b) -> buf[k*32 + (b ^ ((k>>2)&31))]
__device__ __forceinline__ void stage_rows(float* buf, const float* __restrict__ src,
                                           size_t rstride) {
  const int t = threadIdx.x;
#pragma unroll 4
  for (int i = 0; i < 16; i++) {
    int idx4 = i * BD + t;
    int b = idx4 >> 7, k4 = idx4 & 127;
    float4 v = *(const float4*)(src + (size_t)b * rstride + (size_t)(k4 * 4));
    int bw = b ^ (k4 & 31);
    int base = k4 * 128;
    buf[base      + bw] = v.x;
    buf[base + 32 + bw] = v.y;
    buf[base + 64 + bw] = v.z;
    buf[base + 96 + bw] = v.w;
  }
}

__device__ __forceinline__ float lds_at(const float* buf, int k, int b) {
  return buf[k * 32 + (b ^ ((k >> 2) & 31))];
}

// xw_t for THIS WG's 8 preact columns (col = 2w + (c2&1) + (c2>>1)*512),
// returned in a register per thread (t -> b2=t&31, c2=t>>5).
__device__ __forceinline__ float xw_compute(float* buf, const float* __restrict__ x,
                                            const float* __restrict__ W, int tt, int wg) {
  const int t = threadIdx.x;
  __syncthreads();                       // previous buf users done
  stage_rows(buf, x + (size_t)tt * DD, (size_t)TSTEPS * DD);
  __syncthreads();
  const int b = t & 31, s = t >> 5, k0 = s * 64;
  const int d0 = wg * 2;
  float acc[8] = {0.f,0.f,0.f,0.f,0.f,0.f,0.f,0.f};
  for (int k = k0; k < k0 + 64; k++) {
    float hv = lds_at(buf, k, b);
    const float* row = W + (size_t)k * KK4 + d0;
    float2 g0 = *(const float2*)(row);
    float2 g1 = *(const float2*)(row + 512);
    float2 g2 = *(const float2*)(row + 1024);
    float2 g3 = *(const float2*)(row + 1536);
    acc[0] += hv * g0.x; acc[1] += hv * g0.y;
    acc[2] += hv * g1.x; acc[3] += hv * g1.y;
    acc[4] += hv * g2.x; acc[5] += hv * g2.y;
    acc[6] += hv * g3.x; acc[7] += hv * g3.y;
  }
  __syncthreads();
#pragma unroll
  for (int cc = 0; cc < 8; cc++) buf[(cc * 8 + s) * 32 + b] = acc[cc];
  __syncthreads();
  const int b2 = t & 31, c2 = t >> 5;
  float sum = 0.f;
#pragma unroll
  for (int s2 = 0; s2 < 8; s2++) sum += buf[(c2 * 8 + s2) * 32 + b2];
  return sum;
}

__global__ __launch_bounds__(BD, 1) void attn_lstm_persistent(
    const float* __restrict__ x, const float* __restrict__ ctx,
    const float* __restrict__ W, const float* __restrict__ V,
    const float* __restrict__ U, const float* __restrict__ bias,
    const float* __restrict__ Wh, const float* __restrict__ Wc,
    const float* __restrict__ batt, const float* __restrict__ wprj,
    float* __restrict__ out, float* __restrict__ ws) {
  __shared__ float buf[16384];           // 64 KB
  __shared__ float aux[576];
  const int w = blockIdx.x;
  const int t = threadIdx.x;
  float* hatt  = ws + OFF_HATT;
  float* att   = ws + OFF_ATT;
  float* wctxr = ws + OFF_WCTXR;
  float* Zr    = ws + OFF_ZR;
  int*   bar   = (int*)(ws + OFF_BAR);
  int gen = 0;

  const int b2g = t & 31, c2g = t >> 5;          // global thread->output mapping
  const int d0 = w * 2;
  const int mycol = d0 + (c2g & 1) + (c2g >> 1) * 512;
  const float bias_reg = bias[mycol];

  float xw_cur, xw_next = 0.f, hU_reg;
  float c_reg = 0.f;                              // t<64 threads own c[(t&31)][2w+(t>>5)]

  // ---------------- setup: att_ctx = context @ Wc + b_att (WG-local rows) ----------------
  {
    const int r0 = w * 16;
    for (int i = 0; i < 8; i++) {
      int idx4 = i * BD + t;
      int row = idx4 >> 7, c4 = idx4 & 127;
      ((float4*)buf)[idx4] = ((const float4*)(ctx + (size_t)(r0 + row) * DD))[c4];
    }
    __syncthreads();
    float accA[16], accB[16];
#pragma unroll
    for (int r = 0; r < 16; r++) { accA[r] = 0.f; accB[r] = 0.f; }
    const int a0 = t, a1 = t + 256;
    for (int cc = 0; cc < DD; cc++) {
      float w0 = Wc[(size_t)cc * DD + a0];
      float w1 = Wc[(size_t)cc * DD + a1];
#pragma unroll
      for (int r = 0; r < 16; r++) {
        float cv = buf[r * DD + cc];
        accA[r] += cv * w0; accB[r] += cv * w1;
      }
    }
    const float ba0 = batt[a0], ba1 = batt[a1];
    for (int r = 0; r < 16; r++) {
      att[(size_t)(r0 + r) * DD + a0] = accA[r] + ba0;   // normal: same WG reads it later
      att[(size_t)(r0 + r) * DD + a1] = accB[r] + ba1;
    }
  }
  xw_cur = xw_compute(buf, x, W, 0, w);
  gsync(bar, gen);

  // ---------------- recurrence ----------------
  for (int step = 0; step < TSTEPS; step++) {
    // ---- S1: every WG: hU (8 own cols -> reg) + hatt (2 cols, coherent store).
    //      h_{step-1} is read from `out` with NORMAL loads (fresh addresses, L2-cached). ----
    {
      if (step > 0)
        stage_rows(buf, out + (size_t)(step - 1) * DD, (size_t)TSTEPS * DD);
      __syncthreads();
      const int b = t & 31, s = t >> 5, k0 = s * 64;
      float acc[10];
#pragma unroll
      for (int i = 0; i < 10; i++) acc[i] = 0.f;
      if (step > 0) {
        for (int k = k0; k < k0 + 64; k++) {
          float hv = lds_at(buf, k, b);
          const float* row = U + (size_t)k * KK4 + d0;
          float2 g0 = *(const float2*)(row);
          float2 g1 = *(const float2*)(row + 512);
          float2 g2 = *(const float2*)(row + 1024);
          float2 g3 = *(const float2*)(row + 1536);
          float2 wh = *(const float2*)(Wh + (size_t)k * DD + d0);
          acc[0] += hv * g0.x; acc[1] += hv * g0.y;
          acc[2] += hv * g1.x; acc[3] += hv * g1.y;
          acc[4] += hv * g2.x; acc[5] += hv * g2.y;
          acc[6] += hv * g3.x; acc[7] += hv * g3.y;
          acc[8] += hv * wh.x; acc[9] += hv * wh.y;
        }
      }
      __syncthreads();                   // staged h dead
#pragma unroll
      for (int cc = 0; cc < 10; cc++) buf[(cc * 8 + s) * 32 + b] = acc[cc];
      __syncthreads();
      float hu = 0.f;
#pragma unroll
      for (int s2 = 0; s2 < 8; s2++) hu += buf[(c2g * 8 + s2) * 32 + b2g];
      hU_reg = hu;
      if (t < 64) {
        const int b3 = t & 31, j = t >> 5;
        float sum = 0.f;
#pragma unroll
        for (int s2 = 0; s2 < 8; s2++) sum += buf[((8 + j) * 8 + s2) * 32 + b3];
        cstore(hatt + (size_t)b3 * DD + d0 + j, sum);
      }
    }
    gsync(bar, gen);

    // ---- S2: attention scores + unnormalized wctx into ring slot; prefetch xw[t+1] ----
    {
      float* wslot = wctxr + (size_t)step * 16384;
      float* zslot = Zr + (size_t)step * 64;
      const int b = w >> 3, l0 = (w & 7) * 16;
      // stage hatt row b (coherent) into aux[0..512)
      aux[t]       = cload(hatt + (size_t)b * DD + t);
      aux[256 + t] = cload(hatt + (size_t)b * DD + 256 + t);
      __syncthreads();
      const int l = t >> 4, u = t & 15;
      const float* ar = att + (size_t)(b * LC + l0 + l) * DD;
      float p = 0.f;
#pragma unroll
      for (int j = 0; j < 8; j++) {
        int a4 = j * 16 + u;
        float4 av = ((const float4*)ar)[a4];
        float4 wv = ((const float4*)wprj)[a4];
        float hx = aux[a4*4], hy = aux[a4*4+1], hz = aux[a4*4+2], hw = aux[a4*4+3];
        p += ftanh(av.x + hx) * wv.x + ftanh(av.y + hy) * wv.y
           + ftanh(av.z + hz) * wv.z + ftanh(av.w + hw) * wv.w;
      }
      p += __shfl_xor(p, 8); p += __shfl_xor(p, 4);
      p += __shfl_xor(p, 2); p += __shfl_xor(p, 1);
      if (u == 0) {
        float uv = __expf(p);
        aux[512 + l] = uv;
        atomicAdd(&zslot[b], uv);        // device-scope -> MALL
      }
      __syncthreads();
      float s0 = 0.f, s1 = 0.f;
      const float* cr = ctx + (size_t)(b * LC + l0) * DD;
#pragma unroll 4
      for (int l2 = 0; l2 < 16; l2++) {
        float uv = aux[512 + l2];
        s0 += uv * cr[l2 * DD + t];
        s1 += uv * cr[l2 * DD + t + 256];
      }
      atomicAdd(&wslot[(size_t)b * DD + t], s0);
      atomicAdd(&wslot[(size_t)b * DD + t + 256], s1);
      if (step + 1 < TSTEPS) xw_next = xw_compute(buf, x, W, step + 1, w);
    }
    gsync(bar, gen);

    // ---- S3: preact = xw + hU + wctx@V + bias; gates; h/c update.
    //      wctx ring slot read with NORMAL float4 loads (fresh addresses). ----
    {
      stage_rows(buf, wctxr + (size_t)step * 16384, DD);   // raw (unnormalized) wctx
      if (t < 32) aux[t] = Zr[(size_t)step * 64 + t];
      __syncthreads();
      const int b = t & 31, s = t >> 5, k0 = s * 64;
      float acc[8] = {0.f,0.f,0.f,0.f,0.f,0.f,0.f,0.f};
      for (int k = k0; k < k0 + 64; k++) {
        float wv = lds_at(buf, k, b);
        const float* row = V + (size_t)k * KK4 + d0;
        float2 g0 = *(const float2*)(row);
        float2 g1 = *(const float2*)(row + 512);
        float2 g2 = *(const float2*)(row + 1024);
        float2 g3 = *(const float2*)(row + 1536);
        acc[0] += wv * g0.x; acc[1] += wv * g0.y;
        acc[2] += wv * g1.x; acc[3] += wv * g1.y;
        acc[4] += wv * g2.x; acc[5] += wv * g2.y;
        acc[6] += wv * g3.x; acc[7] += wv * g3.y;
      }
      const float rz = rcp_fast(aux[b]);
#pragma unroll
      for (int cc = 0; cc < 8; cc++) acc[cc] *= rz;
      __syncthreads();
#pragma unroll
      for (int cc = 0; cc < 8; cc++) buf[(cc * 8 + s) * 32 + b] = acc[cc];
      __syncthreads();
      {
        float sum = 0.f;
#pragma unroll
        for (int s2 = 0; s2 < 8; s2++) sum += buf[(c2g * 8 + s2) * 32 + b2g];
        sum += xw_cur + hU_reg + bias_reg;
        buf[2048 + c2g * 32 + b2g] = sum;        // disjoint from partials region
      }
      __syncthreads();
      if (t < 64) {
        const int b3 = t & 31, dd = t >> 5;
        const int d = d0 + dd;
        float pi = buf[2048 + (0 + dd) * 32 + b3];
        float pf = buf[2048 + (2 + dd) * 32 + b3];
        float po = buf[2048 + (4 + dd) * 32 + b3];
        float pg = buf[2048 + (6 + dd) * 32 + b3];
        float ig = fsig(pi), fg = fsig(pf), og = fsig(po), gg = ftanh(pg);
        float cn = fg * c_reg + ig * gg;
        c_reg = cn;
        float hn = og * ftanh(cn);
        // h_t == out[:,t,:]; sc1 store -> MALL so next step's S1 normal loads see it
        cstore(out + (size_t)b3 * (TSTEPS * DD) + (size_t)step * DD + d, hn);
      }
      xw_cur = xw_next;
    }
    gsync(bar, gen);
  }
}

extern "C" void kernel_launch(void* const* d_in, const int* in_sizes, int n_in,
                              void* d_out, int out_size, void* d_ws, size_t ws_size,
                              hipStream_t stream) {
  (void)in_sizes; (void)n_in; (void)out_size; (void)ws_size;
  const float* x    = (const float*)d_in[0];
  const float* ctx  = (const float*)d_in[1];
  const float* W    = (const float*)d_in[2];
  const float* V    = (const float*)d_in[3];
  const float* U    = (const float*)d_in[4];
  const float* b    = (const float*)d_in[5];
  const float* Wh   = (const float*)d_in[6];
  const float* Wc   = (const float*)d_in[7];
  const float* batt = (const float*)d_in[8];
  const float* wprj = (const float*)d_in[9];

  // zero the wctx/Z rings (accumulated by atomics) and the barrier counter
  hipMemsetAsync((char*)d_ws + OFF_WCTXR * sizeof(float), 0,
                 (4194304 + 16384) * sizeof(float), stream);
  hipMemsetAsync((char*)d_ws + OFF_BAR * sizeof(float), 0, 64 * sizeof(int), stream);

  hipLaunchKernelGGL(attn_lstm_persistent, dim3(GD), dim3(BD), 0, stream,
                     x, ctx, W, V, U, b, Wh, Wc, batt, wprj,
                     (float*)d_out, (float*)d_ws);
}

// Round 4
// 16704.097 us; speedup vs baseline: 1.0594x; 1.0594x over previous
//
#include <hip/hip_runtime.h>

#define GD 256   // grid (workgroups) -- must be <= CU count for residency
#define BD 256   // block

constexpr int TSTEPS = 256; // sequence length
constexpr int DD = 512;     // d_in = d_out = d_ctx = a_hid
constexpr int KK4 = 2048;   // 4*D_OUT
constexpr int LC = 128;     // context length

constexpr int PCOLS = 26;   // packed cols per WG: 8 W + 8 U + 8 V + 2 Wh
constexpr int PSZ   = PCOLS * DD;  // 13312 floats per WG

// ---- workspace layout (float offsets) ----
constexpr size_t OFF_HATT  = 0;                     // [32][512] row-major (coherent)
constexpr size_t OFF_BAR   = OFF_HATT + 16384;      // barrier ints
constexpr size_t OFF_ATT   = OFF_BAR  + 64;         // [32*128][512] context@Wc + b_att (WG-local)
constexpr size_t OFF_WCTXR = OFF_ATT  + 2097152;    // ring: [256][32][512] (atomics -> MALL)
constexpr size_t OFF_ZR    = OFF_WCTXR + 4194304;   // ring: [256][64]
constexpr size_t OFF_PACK  = OFF_ZR   + 16384;      // [256][26][512] per-WG packed weights
constexpr size_t WS_FLOATS = OFF_PACK + (size_t)GD * PSZ;   // ~38.9 MB total

__device__ __forceinline__ float rcp_fast(float x) { return __builtin_amdgcn_rcpf(x); }
__device__ __forceinline__ float ftanh(float x) {
  float e = __expf(2.0f * x);
  return 1.0f - 2.0f * rcp_fast(e + 1.0f);
}
__device__ __forceinline__ float fsig(float x) { return rcp_fast(1.0f + __expf(-x)); }

// coherent (agent-scope, L2-bypassing) scalar access -- does NOT invalidate L2
__device__ __forceinline__ float cload(const float* p) {
  return __hip_atomic_load(p, __ATOMIC_RELAXED, __HIP_MEMORY_SCOPE_AGENT);
}
__device__ __forceinline__ void cstore(float* p, float v) {
  __hip_atomic_store(p, v, __ATOMIC_RELAXED, __HIP_MEMORY_SCOPE_AGENT);
}

// grid barrier: __syncthreads drains each wave's vmcnt (cross-WG stores are
// sc-coherent and land at MALL); relaxed agent add + spin; NO cache invalidation.
__device__ __forceinline__ void gsync(int* bar, int& gen) {
  __syncthreads();
  if (threadIdx.x == 0) {
    gen++;
    __hip_atomic_fetch_add(bar, 1, __ATOMIC_RELAXED, __HIP_MEMORY_SCOPE_AGENT);
    const int target = gen * GD;
    while (__hip_atomic_load(bar, __ATOMIC_RELAXED, __HIP_MEMORY_SCOPE_AGENT) < target)
      __builtin_amdgcn_s_sleep(2);
    asm volatile("" ::: "memory");
  }
  __syncthreads();
}

// Stage 32 rows x 512 cols (row stride rstride) into LDS transposed + XOR-swizzled,
// NORMAL cached loads. (k,b) -> buf[k*32 + (b ^ ((k>>2)&31))]
__device__ __forceinline__ void stage_rows(float* buf, const float* __restrict__ src,
                                           size_t rstride) {
  const int t = threadIdx.x;
#pragma unroll 4
  for (int i = 0; i < 16; i++) {
    int idx4 = i * BD + t;
    int b = idx4 >> 7, k4 = idx4 & 127;
    float4 v = *(const float4*)(src + (size_t)b * rstride + (size_t)(k4 * 4));
    int bw = b ^ (k4 & 31);
    int base = k4 * 128;
    buf[base      + bw] = v.x;
    buf[base + 32 + bw] = v.y;
    buf[base + 64 + bw] = v.z;
    buf[base + 96 + bw] = v.w;
  }
}

__device__ __forceinline__ float lds_at(const float* buf, int k, int b) {
  return buf[k * 32 + (b ^ ((k >> 2) & 31))];
}

// 8-col K-slice MAC with packed (k-contiguous) weights: acc[c] += h[k,b]*P[c][k]
__device__ __forceinline__ void mac8(const float* buf, const float* __restrict__ P,
                                     int k0, int b, float* acc) {
  for (int kk = k0; kk < k0 + 64; kk += 4) {
    float h0 = lds_at(buf, kk + 0, b), h1 = lds_at(buf, kk + 1, b);
    float h2 = lds_at(buf, kk + 2, b), h3 = lds_at(buf, kk + 3, b);
#pragma unroll
    for (int c = 0; c < 8; c++) {
      float4 wv = *(const float4*)(P + c * DD + kk);
      acc[c] += h0 * wv.x + h1 * wv.y + h2 * wv.z + h3 * wv.w;
    }
  }
}

// xw_t for THIS WG's 8 preact columns (col = 2w + (c&1) + (c>>1)*512),
// returned in a register per thread (t -> b2=t&31, c2=t>>5).
__device__ __forceinline__ float xw_compute(float* buf, const float* __restrict__ x,
                                            const float* __restrict__ PW, int tt) {
  const int t = threadIdx.x;
  __syncthreads();                       // previous buf users done
  stage_rows(buf, x + (size_t)tt * DD, (size_t)TSTEPS * DD);
  __syncthreads();
  const int b = t & 31, s = t >> 5, k0 = s * 64;
  float acc[8] = {0.f,0.f,0.f,0.f,0.f,0.f,0.f,0.f};
  mac8(buf, PW, k0, b, acc);
  __syncthreads();
#pragma unroll
  for (int cc = 0; cc < 8; cc++) buf[(cc * 8 + s) * 32 + b] = acc[cc];
  __syncthreads();
  const int b2 = t & 31, c2 = t >> 5;
  float sum = 0.f;
#pragma unroll
  for (int s2 = 0; s2 < 8; s2++) sum += buf[(c2 * 8 + s2) * 32 + b2];
  return sum;
}

__global__ __launch_bounds__(BD, 1) void attn_lstm_persistent(
    const float* __restrict__ x, const float* __restrict__ ctx,
    const float* __restrict__ W, const float* __restrict__ V,
    const float* __restrict__ U, const float* __restrict__ bias,
    const float* __restrict__ Wh, const float* __restrict__ Wc,
    const float* __restrict__ batt, const float* __restrict__ wprj,
    float* __restrict__ out, float* __restrict__ ws) {
  __shared__ float buf[16384];           // 64 KB
  __shared__ float aux[576];
  const int w = blockIdx.x;
  const int t = threadIdx.x;
  float* hatt  = ws + OFF_HATT;
  float* att   = ws + OFF_ATT;
  float* wctxr = ws + OFF_WCTXR;
  float* Zr    = ws + OFF_ZR;
  float* packb = ws + OFF_PACK + (size_t)w * PSZ;
  int*   bar   = (int*)(ws + OFF_BAR);
  int gen = 0;

  const int b2g = t & 31, c2g = t >> 5;          // global thread->output mapping
  const int d0 = w * 2;
  const int mycol = d0 + (c2g & 1) + (c2g >> 1) * 512;
  const float bias_reg = bias[mycol];

  float xw_cur, xw_next = 0.f, hU_reg;
  float c_reg = 0.f;                              // t<64 threads own c[(t&31)][2w+(t>>5)]

  // ---------------- setup A: pack this WG's 26 weight columns k-contiguous ----------------
  {
#pragma unroll 4
    for (int i = 0; i < PCOLS * 2; i++) {         // 52 iterations x 256 threads
      int e = i * BD + t;
      int pc = e >> 9, k = e & 511;
      float v;
      if (pc < 8)       v = W[(size_t)k * KK4 + d0 + (pc & 1) + (pc >> 1) * 512];
      else if (pc < 16) { int q = pc - 8;  v = U[(size_t)k * KK4 + d0 + (q & 1) + (q >> 1) * 512]; }
      else if (pc < 24) { int q = pc - 16; v = V[(size_t)k * KK4 + d0 + (q & 1) + (q >> 1) * 512]; }
      else              v = Wh[(size_t)k * DD + d0 + (pc - 24)];
      packb[e] = v;
    }
  }
  const float* PW  = packb;
  const float* PU  = packb + 8 * DD;
  const float* PV  = packb + 16 * DD;
  const float* PWh = packb + 24 * DD;
  __syncthreads();

  // ---------------- setup B: att_ctx = context @ Wc + b_att (WG-local rows) ----------------
  {
    const int r0 = w * 16;
    for (int i = 0; i < 8; i++) {
      int idx4 = i * BD + t;
      int row = idx4 >> 7, c4 = idx4 & 127;
      ((float4*)buf)[idx4] = ((const float4*)(ctx + (size_t)(r0 + row) * DD))[c4];
    }
    __syncthreads();
    float accA[16], accB[16];
#pragma unroll
    for (int r = 0; r < 16; r++) { accA[r] = 0.f; accB[r] = 0.f; }
    const int a0 = t, a1 = t + 256;
    for (int cc = 0; cc < DD; cc++) {
      float w0 = Wc[(size_t)cc * DD + a0];
      float w1 = Wc[(size_t)cc * DD + a1];
#pragma unroll
      for (int r = 0; r < 16; r++) {
        float cv = buf[r * DD + cc];
        accA[r] += cv * w0; accB[r] += cv * w1;
      }
    }
    const float ba0 = batt[a0], ba1 = batt[a1];
    for (int r = 0; r < 16; r++) {
      att[(size_t)(r0 + r) * DD + a0] = accA[r] + ba0;   // normal: same WG reads it later
      att[(size_t)(r0 + r) * DD + a1] = accB[r] + ba1;
    }
  }
  xw_cur = xw_compute(buf, x, PW, 0);
  gsync(bar, gen);

  // ---------------- recurrence ----------------
  for (int step = 0; step < TSTEPS; step++) {
    // ---- S1: every WG: hU (8 own cols -> reg) + hatt (2 cols, coherent store).
    //      h_{step-1} is read from `out` with NORMAL loads (fresh addresses). ----
    {
      if (step > 0)
        stage_rows(buf, out + (size_t)(step - 1) * DD, (size_t)TSTEPS * DD);
      __syncthreads();
      const int b = t & 31, s = t >> 5, k0 = s * 64;
      float acc[10];
#pragma unroll
      for (int i = 0; i < 10; i++) acc[i] = 0.f;
      if (step > 0) {
        mac8(buf, PU, k0, b, acc);
        for (int kk = k0; kk < k0 + 64; kk += 4) {
          float h0 = lds_at(buf, kk + 0, b), h1 = lds_at(buf, kk + 1, b);
          float h2 = lds_at(buf, kk + 2, b), h3 = lds_at(buf, kk + 3, b);
          float4 w0 = *(const float4*)(PWh + kk);
          float4 w1 = *(const float4*)(PWh + DD + kk);
          acc[8] += h0 * w0.x + h1 * w0.y + h2 * w0.z + h3 * w0.w;
          acc[9] += h0 * w1.x + h1 * w1.y + h2 * w1.z + h3 * w1.w;
        }
      }
      __syncthreads();                   // staged h dead
#pragma unroll
      for (int cc = 0; cc < 10; cc++) buf[(cc * 8 + s) * 32 + b] = acc[cc];
      __syncthreads();
      float hu = 0.f;
#pragma unroll
      for (int s2 = 0; s2 < 8; s2++) hu += buf[(c2g * 8 + s2) * 32 + b2g];
      hU_reg = hu;
      if (t < 64) {
        const int b3 = t & 31, j = t >> 5;
        float sum = 0.f;
#pragma unroll
        for (int s2 = 0; s2 < 8; s2++) sum += buf[((8 + j) * 8 + s2) * 32 + b3];
        cstore(hatt + (size_t)b3 * DD + d0 + j, sum);
      }
    }
    gsync(bar, gen);

    // ---- S2: attention scores + unnormalized wctx into ring slot; prefetch xw[t+1] ----
    {
      float* wslot = wctxr + (size_t)step * 16384;
      float* zslot = Zr + (size_t)step * 64;
      const int b = w >> 3, l0 = (w & 7) * 16;
      // stage hatt row b (coherent) into aux[0..512)
      aux[t]       = cload(hatt + (size_t)b * DD + t);
      aux[256 + t] = cload(hatt + (size_t)b * DD + 256 + t);
      __syncthreads();
      const int l = t >> 4, u = t & 15;
      const float* ar = att + (size_t)(b * LC + l0 + l) * DD;
      float p = 0.f;
#pragma unroll
      for (int j = 0; j < 8; j++) {
        int a4 = j * 16 + u;
        float4 av = ((const float4*)ar)[a4];
        float4 wv = ((const float4*)wprj)[a4];
        float hx = aux[a4*4], hy = aux[a4*4+1], hz = aux[a4*4+2], hw = aux[a4*4+3];
        p += ftanh(av.x + hx) * wv.x + ftanh(av.y + hy) * wv.y
           + ftanh(av.z + hz) * wv.z + ftanh(av.w + hw) * wv.w;
      }
      p += __shfl_xor(p, 8); p += __shfl_xor(p, 4);
      p += __shfl_xor(p, 2); p += __shfl_xor(p, 1);
      if (u == 0) {
        float uv = __expf(p);
        aux[512 + l] = uv;
        atomicAdd(&zslot[b], uv);        // device-scope -> MALL
      }
      __syncthreads();
      float s0 = 0.f, s1 = 0.f;
      const float* cr = ctx + (size_t)(b * LC + l0) * DD;
#pragma unroll 4
      for (int l2 = 0; l2 < 16; l2++) {
        float uv = aux[512 + l2];
        s0 += uv * cr[l2 * DD + t];
        s1 += uv * cr[l2 * DD + t + 256];
      }
      atomicAdd(&wslot[(size_t)b * DD + t], s0);
      atomicAdd(&wslot[(size_t)b * DD + t + 256], s1);
      if (step + 1 < TSTEPS) xw_next = xw_compute(buf, x, PW, step + 1);
    }
    gsync(bar, gen);

    // ---- S3: preact = xw + hU + wctx@V + bias; gates; h/c update.
    //      wctx ring slot read with NORMAL float4 loads (fresh addresses). ----
    {
      stage_rows(buf, wctxr + (size_t)step * 16384, DD);   // raw (unnormalized) wctx
      if (t < 32) aux[t] = Zr[(size_t)step * 64 + t];
      __syncthreads();
      const int b = t & 31, s = t >> 5, k0 = s * 64;
      float acc[8] = {0.f,0.f,0.f,0.f,0.f,0.f,0.f,0.f};
      mac8(buf, PV, k0, b, acc);
      const float rz = rcp_fast(aux[b]);
#pragma unroll
      for (int cc = 0; cc < 8; cc++) acc[cc] *= rz;
      __syncthreads();
#pragma unroll
      for (int cc = 0; cc < 8; cc++) buf[(cc * 8 + s) * 32 + b] = acc[cc];
      __syncthreads();
      {
        float sum = 0.f;
#pragma unroll
        for (int s2 = 0; s2 < 8; s2++) sum += buf[(c2g * 8 + s2) * 32 + b2g];
        sum += xw_cur + hU_reg + bias_reg;
        buf[2048 + c2g * 32 + b2g] = sum;        // disjoint from partials region
      }
      __syncthreads();
      if (t < 64) {
        const int b3 = t & 31, dd = t >> 5;
        const int d = d0 + dd;
        float pi = buf[2048 + (0 + dd) * 32 + b3];
        float pf = buf[2048 + (2 + dd) * 32 + b3];
        float po = buf[2048 + (4 + dd) * 32 + b3];
        float pg = buf[2048 + (6 + dd) * 32 + b3];
        float ig = fsig(pi), fg = fsig(pf), og = fsig(po), gg = ftanh(pg);
        float cn = fg * c_reg + ig * gg;
        c_reg = cn;
        float hn = og * ftanh(cn);
        // h_t == out[:,t,:]; sc1 store -> MALL so next step's S1 normal loads see it
        cstore(out + (size_t)b3 * (TSTEPS * DD) + (size_t)step * DD + d, hn);
      }
      xw_cur = xw_next;
    }
    gsync(bar, gen);
  }
}

extern "C" void kernel_launch(void* const* d_in, const int* in_sizes, int n_in,
                              void* d_out, int out_size, void* d_ws, size_t ws_size,
                              hipStream_t stream) {
  (void)in_sizes; (void)n_in; (void)out_size; (void)ws_size;
  const float* x    = (const float*)d_in[0];
  const float* ctx  = (const float*)d_in[1];
  const float* W    = (const float*)d_in[2];
  const float* V    = (const float*)d_in[3];
  const float* U    = (const float*)d_in[4];
  const float* b    = (const float*)d_in[5];
  const float* Wh   = (const float*)d_in[6];
  const float* Wc   = (const float*)d_in[7];
  const float* batt = (const float*)d_in[8];
  const float* wprj = (const float*)d_in[9];

  // zero the wctx/Z rings (accumulated by atomics) and the barrier counter
  hipMemsetAsync((char*)d_ws + OFF_WCTXR * sizeof(float), 0,
                 (4194304 + 16384) * sizeof(float), stream);
  hipMemsetAsync((char*)d_ws + OFF_BAR * sizeof(float), 0, 64 * sizeof(int), stream);

  hipLaunchKernelGGL(attn_lstm_persistent, dim3(GD), dim3(BD), 0, stream,
                     x, ctx, W, V, U, b, Wh, Wc, batt, wprj,
                     (float*)d_out, (float*)d_ws);
}

// Round 5
// 10672.054 us; speedup vs baseline: 1.6583x; 1.5652x over previous
//
#include <hip/hip_runtime.h>

#define GD 256   // grid (workgroups) -- must be <= CU count for residency
#define BD 256   // block

constexpr int TSTEPS = 256; // sequence length
constexpr int DD = 512;     // d_in = d_out = d_ctx = a_hid
constexpr int KK4 = 2048;   // 4*D_OUT
constexpr int LC = 128;     // context length

constexpr int PCOLS = 26;   // packed cols per WG: 8 W + 8 U + 8 V + 2 Wh
constexpr int PSZ   = PCOLS * DD;  // 13312 floats per WG

// ---- workspace layout (float offsets) ----
constexpr size_t OFF_HATT  = 0;                     // [32][512] row-major (coherent)
constexpr size_t OFF_BAR   = OFF_HATT + 16384;      // 256 ints: [0]=arrive, [16+i*16]=release lines
constexpr size_t OFF_ATT   = OFF_BAR  + 256;        // [32*128][512] context@Wc + b_att (WG-local)
constexpr size_t OFF_WCTXR = OFF_ATT  + 2097152;    // ring: [256][32][512] (atomics -> MALL)
constexpr size_t OFF_ZR    = OFF_WCTXR + 4194304;   // ring: [256][64]
constexpr size_t OFF_PACK  = OFF_ZR   + 16384;      // [256][26][512] per-WG packed weights
constexpr size_t WS_FLOATS = OFF_PACK + (size_t)GD * PSZ;   // ~38.9 MB total

__device__ __forceinline__ float rcp_fast(float x) { return __builtin_amdgcn_rcpf(x); }
__device__ __forceinline__ float ftanh(float x) {
  float e = __expf(2.0f * x);
  return 1.0f - 2.0f * rcp_fast(e + 1.0f);
}
__device__ __forceinline__ float fsig(float x) { return rcp_fast(1.0f + __expf(-x)); }

__device__ __forceinline__ float dot4(float4 a, float4 b) {
  return a.x * b.x + a.y * b.y + a.z * b.z + a.w * b.w;
}

// coherent (agent-scope, L2-bypassing) scalar access -- does NOT invalidate L2
__device__ __forceinline__ float cload(const float* p) {
  return __hip_atomic_load(p, __ATOMIC_RELAXED, __HIP_MEMORY_SCOPE_AGENT);
}
__device__ __forceinline__ void cstore(float* p, float v) {
  __hip_atomic_store(p, v, __ATOMIC_RELAXED, __HIP_MEMORY_SCOPE_AGENT);
}

// grid barrier, low-contention: arrivals fetch_add bar[0]; LAST arriver (knows from
// returned old value) stores gen to 8 separate release lines; spinners poll only
// their release line (read-only). Poll traffic never collides with the RMW stream.
__device__ __forceinline__ void gsync(int* bar, int w, int& gen) {
  __syncthreads();
  if (threadIdx.x == 0) {
    gen++;
    int old = __hip_atomic_fetch_add(bar, 1, __ATOMIC_RELAXED, __HIP_MEMORY_SCOPE_AGENT);
    if (old == gen * GD - 1) {
#pragma unroll
      for (int i = 0; i < 8; i++)
        __hip_atomic_store(bar + 16 + i * 16, gen, __ATOMIC_RELAXED,
                           __HIP_MEMORY_SCOPE_AGENT);
    } else {
      const int* rel = bar + 16 + (w & 7) * 16;
      while (__hip_atomic_load(rel, __ATOMIC_RELAXED, __HIP_MEMORY_SCOPE_AGENT) < gen)
        __builtin_amdgcn_s_sleep(2);
    }
    asm volatile("" ::: "memory");
  }
  __syncthreads();
}

// xw_t for THIS WG's 8 preact columns; h-row read DIRECTLY from global (no LDS
// staging). Thread t -> (b=t&31, s=t>>5) accumulates k-slice [64s,64s+64).
__device__ __forceinline__ float xw_compute(float* buf, const float* __restrict__ x,
                                            const float* __restrict__ PW, int tt,
                                            int b2g, int c2g) {
  const int t = threadIdx.x, b = t & 31, s = t >> 5, k0 = s * 64;
  const float* hrow = x + ((size_t)b * TSTEPS + tt) * DD + k0;
  const float* Pk = PW + k0;
  float acc[8] = {0.f,0.f,0.f,0.f,0.f,0.f,0.f,0.f};
#pragma unroll 4
  for (int kk = 0; kk < 64; kk += 4) {
    float4 hv = *(const float4*)(hrow + kk);
#pragma unroll
    for (int c = 0; c < 8; c++)
      acc[c] += dot4(hv, *(const float4*)(Pk + c * DD + kk));
  }
  __syncthreads();                       // previous buf users done
#pragma unroll
  for (int cc = 0; cc < 8; cc++) buf[(cc * 8 + s) * 32 + b] = acc[cc];
  __syncthreads();
  float sum = 0.f;
#pragma unroll
  for (int s2 = 0; s2 < 8; s2++) sum += buf[(c2g * 8 + s2) * 32 + b2g];
  return sum;
}

__global__ __launch_bounds__(BD, 1) void attn_lstm_persistent(
    const float* __restrict__ x, const float* __restrict__ ctx,
    const float* __restrict__ W, const float* __restrict__ V,
    const float* __restrict__ U, const float* __restrict__ bias,
    const float* __restrict__ Wh, const float* __restrict__ Wc,
    const float* __restrict__ batt, const float* __restrict__ wprj,
    float* __restrict__ out, float* __restrict__ ws) {
  __shared__ float buf[16384];           // 64 KB (setup staging + reductions)
  __shared__ float aux[576];
  const int w = blockIdx.x;
  const int t = threadIdx.x;
  float* hatt  = ws + OFF_HATT;
  float* att   = ws + OFF_ATT;
  float* wctxr = ws + OFF_WCTXR;
  float* Zr    = ws + OFF_ZR;
  float* packb = ws + OFF_PACK + (size_t)w * PSZ;
  int*   bar   = (int*)(ws + OFF_BAR);
  int gen = 0;

  const int b2g = t & 31, c2g = t >> 5;          // thread->output mapping
  const int d0 = w * 2;
  const int mycol = d0 + (c2g & 1) + (c2g >> 1) * 512;
  const float bias_reg = bias[mycol];

  float xw_cur, xw_next = 0.f, hU_reg;
  float c_reg = 0.f;                              // t<64 threads own c[(t&31)][2w+(t>>5)]

  // ---------------- setup A: pack this WG's 26 weight columns k-contiguous ----------------
  {
#pragma unroll 4
    for (int i = 0; i < PCOLS * 2; i++) {         // 52 iterations x 256 threads
      int e = i * BD + t;
      int pc = e >> 9, k = e & 511;
      float v;
      if (pc < 8)       v = W[(size_t)k * KK4 + d0 + (pc & 1) + (pc >> 1) * 512];
      else if (pc < 16) { int q = pc - 8;  v = U[(size_t)k * KK4 + d0 + (q & 1) + (q >> 1) * 512]; }
      else if (pc < 24) { int q = pc - 16; v = V[(size_t)k * KK4 + d0 + (q & 1) + (q >> 1) * 512]; }
      else              v = Wh[(size_t)k * DD + d0 + (pc - 24)];
      packb[e] = v;
    }
  }
  const float* PW  = packb;
  const float* PU  = packb + 8 * DD;
  const float* PV  = packb + 16 * DD;
  const float* PWh = packb + 24 * DD;
  __syncthreads();

  // ---------------- setup B: att_ctx = context @ Wc + b_att (WG-local rows) ----------------
  {
    const int r0 = w * 16;
    for (int i = 0; i < 8; i++) {
      int idx4 = i * BD + t;
      int row = idx4 >> 7, c4 = idx4 & 127;
      ((float4*)buf)[idx4] = ((const float4*)(ctx + (size_t)(r0 + row) * DD))[c4];
    }
    __syncthreads();
    float accA[16], accB[16];
#pragma unroll
    for (int r = 0; r < 16; r++) { accA[r] = 0.f; accB[r] = 0.f; }
    const int a0 = t, a1 = t + 256;
    for (int cc = 0; cc < DD; cc++) {
      float w0 = Wc[(size_t)cc * DD + a0];
      float w1 = Wc[(size_t)cc * DD + a1];
#pragma unroll
      for (int r = 0; r < 16; r++) {
        float cv = buf[r * DD + cc];
        accA[r] += cv * w0; accB[r] += cv * w1;
      }
    }
    const float ba0 = batt[a0], ba1 = batt[a1];
    for (int r = 0; r < 16; r++) {
      att[(size_t)(r0 + r) * DD + a0] = accA[r] + ba0;   // normal: same WG reads it later
      att[(size_t)(r0 + r) * DD + a1] = accB[r] + ba1;
    }
  }
  xw_cur = xw_compute(buf, x, PW, 0, b2g, c2g);
  gsync(bar, w, gen);

  // ---------------- recurrence ----------------
  for (int step = 0; step < TSTEPS; step++) {
    // ---- S1: hU (8 own cols -> reg) + hatt (2 cols, coherent store).
    //      h_{step-1} == out[:,step-1,:], read directly (L2-cached, fresh lines). ----
    {
      const int b = t & 31, s = t >> 5, k0 = s * 64;
      float acc[10];
#pragma unroll
      for (int i = 0; i < 10; i++) acc[i] = 0.f;
      if (step > 0) {
        const float* hrow = out + (size_t)b * (TSTEPS * DD) + (size_t)(step - 1) * DD + k0;
        const float* Pk   = PU + k0;
        const float* Pwh  = PWh + k0;
#pragma unroll 4
        for (int kk = 0; kk < 64; kk += 4) {
          float4 hv = *(const float4*)(hrow + kk);
#pragma unroll
          for (int c = 0; c < 8; c++)
            acc[c] += dot4(hv, *(const float4*)(Pk + c * DD + kk));
          acc[8] += dot4(hv, *(const float4*)(Pwh + kk));
          acc[9] += dot4(hv, *(const float4*)(Pwh + DD + kk));
        }
      }
#pragma unroll
      for (int cc = 0; cc < 10; cc++) buf[(cc * 8 + s) * 32 + b] = acc[cc];
      __syncthreads();
      float hu = 0.f;
#pragma unroll
      for (int s2 = 0; s2 < 8; s2++) hu += buf[(c2g * 8 + s2) * 32 + b2g];
      hU_reg = hu;
      if (t < 64) {
        const int b3 = t & 31, j = t >> 5;
        float sum = 0.f;
#pragma unroll
        for (int s2 = 0; s2 < 8; s2++) sum += buf[((8 + j) * 8 + s2) * 32 + b3];
        cstore(hatt + (size_t)b3 * DD + d0 + j, sum);
      }
    }
    gsync(bar, w, gen);

    // ---- S2: attention scores + unnormalized wctx into ring slot; prefetch xw[t+1] ----
    {
      float* wslot = wctxr + (size_t)step * 16384;
      float* zslot = Zr + (size_t)step * 64;
      const int b = w >> 3, l0 = (w & 7) * 16;
      // stage hatt row b (coherent) into aux[0..512)
      aux[t]       = cload(hatt + (size_t)b * DD + t);
      aux[256 + t] = cload(hatt + (size_t)b * DD + 256 + t);
      __syncthreads();
      const int l = t >> 4, u = t & 15;
      const float* ar = att + (size_t)(b * LC + l0 + l) * DD;
      float p = 0.f;
#pragma unroll
      for (int j = 0; j < 8; j++) {
        int a4 = j * 16 + u;
        float4 av = ((const float4*)ar)[a4];
        float4 wv = ((const float4*)wprj)[a4];
        float hx = aux[a4*4], hy = aux[a4*4+1], hz = aux[a4*4+2], hw = aux[a4*4+3];
        p += ftanh(av.x + hx) * wv.x + ftanh(av.y + hy) * wv.y
           + ftanh(av.z + hz) * wv.z + ftanh(av.w + hw) * wv.w;
      }
      p += __shfl_xor(p, 8); p += __shfl_xor(p, 4);
      p += __shfl_xor(p, 2); p += __shfl_xor(p, 1);
      if (u == 0) {
        float uv = __expf(p);
        aux[512 + l] = uv;
        atomicAdd(&zslot[b], uv);        // device-scope -> MALL
      }
      __syncthreads();
      float s0 = 0.f, s1 = 0.f;
      const float* cr = ctx + (size_t)(b * LC + l0) * DD;
#pragma unroll 4
      for (int l2 = 0; l2 < 16; l2++) {
        float uv = aux[512 + l2];
        s0 += uv * cr[l2 * DD + t];
        s1 += uv * cr[l2 * DD + t + 256];
      }
      atomicAdd(&wslot[(size_t)b * DD + t], s0);
      atomicAdd(&wslot[(size_t)b * DD + t + 256], s1);
      if (step + 1 < TSTEPS) xw_next = xw_compute(buf, x, PW, step + 1, b2g, c2g);
    }
    gsync(bar, w, gen);

    // ---- S3: preact = xw + hU + wctx@V + bias; gates; h/c update.
    //      wctx ring slot read directly (fresh lines). ----
    {
      const int b = t & 31, s = t >> 5, k0 = s * 64;
      if (t < 32) aux[t] = Zr[(size_t)step * 64 + t];
      const float* wrow = wctxr + (size_t)step * 16384 + (size_t)b * DD + k0;
      const float* Pk   = PV + k0;
      float acc[8] = {0.f,0.f,0.f,0.f,0.f,0.f,0.f,0.f};
#pragma unroll 4
      for (int kk = 0; kk < 64; kk += 4) {
        float4 hv = *(const float4*)(wrow + kk);
#pragma unroll
        for (int c = 0; c < 8; c++)
          acc[c] += dot4(hv, *(const float4*)(Pk + c * DD + kk));
      }
      __syncthreads();                   // aux (Z) visible
      const float rz = rcp_fast(aux[b]);
#pragma unroll
      for (int cc = 0; cc < 8; cc++) buf[(cc * 8 + s) * 32 + b] = acc[cc] * rz;
      __syncthreads();
      {
        float sum = 0.f;
#pragma unroll
        for (int s2 = 0; s2 < 8; s2++) sum += buf[(c2g * 8 + s2) * 32 + b2g];
        sum += xw_cur + hU_reg + bias_reg;
        buf[2048 + c2g * 32 + b2g] = sum;        // disjoint from partials region
      }
      __syncthreads();
      if (t < 64) {
        const int b3 = t & 31, dd = t >> 5;
        const int d = d0 + dd;
        float pi = buf[2048 + (0 + dd) * 32 + b3];
        float pf = buf[2048 + (2 + dd) * 32 + b3];
        float po = buf[2048 + (4 + dd) * 32 + b3];
        float pg = buf[2048 + (6 + dd) * 32 + b3];
        float ig = fsig(pi), fg = fsig(pf), og = fsig(po), gg = ftanh(pg);
        float cn = fg * c_reg + ig * gg;
        c_reg = cn;
        float hn = og * ftanh(cn);
        // h_t == out[:,t,:]; sc1 store -> MALL so next step's S1 loads see it
        cstore(out + (size_t)b3 * (TSTEPS * DD) + (size_t)step * DD + d, hn);
      }
      xw_cur = xw_next;
    }
    gsync(bar, w, gen);
  }
}

extern "C" void kernel_launch(void* const* d_in, const int* in_sizes, int n_in,
                              void* d_out, int out_size, void* d_ws, size_t ws_size,
                              hipStream_t stream) {
  (void)in_sizes; (void)n_in; (void)out_size; (void)ws_size;
  const float* x    = (const float*)d_in[0];
  const float* ctx  = (const float*)d_in[1];
  const float* W    = (const float*)d_in[2];
  const float* V    = (const float*)d_in[3];
  const float* U    = (const float*)d_in[4];
  const float* b    = (const float*)d_in[5];
  const float* Wh   = (const float*)d_in[6];
  const float* Wc   = (const float*)d_in[7];
  const float* batt = (const float*)d_in[8];
  const float* wprj = (const float*)d_in[9];

  // zero the wctx/Z rings (accumulated by atomics) and the barrier region
  hipMemsetAsync((char*)d_ws + OFF_WCTXR * sizeof(float), 0,
                 (4194304 + 16384) * sizeof(float), stream);
  hipMemsetAsync((char*)d_ws + OFF_BAR * sizeof(float), 0, 256 * sizeof(int), stream);

  hipLaunchKernelGGL(attn_lstm_persistent, dim3(GD), dim3(BD), 0, stream,
                     x, ctx, W, V, U, b, Wh, Wc, batt, wprj,
                     (float*)d_out, (float*)d_ws);
}

// Round 6
// 9743.040 us; speedup vs baseline: 1.8164x; 1.0954x over previous
//
#include <hip/hip_runtime.h>

#define GD 256   // grid (workgroups) -- must be <= CU count for residency
#define BD 256   // block

constexpr int TSTEPS = 256; // sequence length
constexpr int DD = 512;     // d_in = d_out = d_ctx = a_hid
constexpr int KK4 = 2048;   // 4*D_OUT
constexpr int LC = 128;     // context length

constexpr int PCOLS = 26;   // packed cols per WG: 8 W + 8 U + 8 V + 2 Wh
constexpr int PSZ   = PCOLS * DD;  // 13312 floats per WG

// ---- workspace layout (float offsets) ----
constexpr size_t OFF_HATT  = 0;                     // [32][512] row-major (coherent)
constexpr size_t OFF_FLAGS = 16384;                 // 256 arrival flags, stride 32 ints (own line each)
constexpr size_t OFF_REL   = OFF_FLAGS + 8192;      // 8 release lines, stride 32 ints
constexpr size_t OFF_ATT   = OFF_REL + 256;         // [32*128][512] context@Wc + b_att (WG-local)
constexpr size_t OFF_WCTXR = OFF_ATT  + 2097152;    // ring: [256][32][512] (atomics -> MALL)
constexpr size_t OFF_ZR    = OFF_WCTXR + 4194304;   // ring: [256][64]
constexpr size_t OFF_PACK  = OFF_ZR   + 16384;      // [256][26][512] per-WG packed weights
constexpr size_t WS_FLOATS = OFF_PACK + (size_t)GD * PSZ;   // ~39 MB total

__device__ __forceinline__ float rcp_fast(float x) { return __builtin_amdgcn_rcpf(x); }
__device__ __forceinline__ float ftanh(float x) {
  float e = __expf(2.0f * x);
  return 1.0f - 2.0f * rcp_fast(e + 1.0f);
}
__device__ __forceinline__ float fsig(float x) { return rcp_fast(1.0f + __expf(-x)); }

__device__ __forceinline__ float dot4(float4 a, float4 b) {
  return a.x * b.x + a.y * b.y + a.z * b.z + a.w * b.w;
}

// coherent (agent-scope, L2-bypassing) scalar access -- does NOT invalidate L2
__device__ __forceinline__ float cload(const float* p) {
  return __hip_atomic_load(p, __ATOMIC_RELAXED, __HIP_MEMORY_SCOPE_AGENT);
}
__device__ __forceinline__ void cstore(float* p, float v) {
  __hip_atomic_store(p, v, __ATOMIC_RELAXED, __HIP_MEMORY_SCOPE_AGENT);
}

// grid barrier with NO atomic RMW (same-line RMW serialization at MALL was
// ~110 cyc x 256 WGs = ~12 us/barrier in R5). Arrival: each WG stores gen to
// its OWN flag line. Detection: WG0 wave0 scans all 256 flags in parallel
// (4 loads/lane). Release: 8 separate lines; spinners poll their line only.
__device__ __forceinline__ void gsync(int* flags, int* rel, int w, int& gen) {
  __syncthreads();
  gen++;
  const int t = threadIdx.x;
  if (w == 0) {
    if (t < 64) {
      if (t == 0)
        __hip_atomic_store(flags, gen, __ATOMIC_RELAXED, __HIP_MEMORY_SCOPE_AGENT);
      for (;;) {
        int m = gen;
#pragma unroll
        for (int i = 0; i < 4; i++) {
          int v = __hip_atomic_load(flags + (t + i * 64) * 32,
                                    __ATOMIC_RELAXED, __HIP_MEMORY_SCOPE_AGENT);
          m = (v < m) ? v : m;
        }
        if (__all(m >= gen)) break;      // one MALL sweep per poll (~0.4 us)
      }
      if (t == 0) {
#pragma unroll
        for (int i = 0; i < 8; i++)
          __hip_atomic_store(rel + i * 32, gen, __ATOMIC_RELAXED,
                             __HIP_MEMORY_SCOPE_AGENT);
      }
    }
    asm volatile("" ::: "memory");
  } else {
    if (t == 0) {
      __hip_atomic_store(flags + w * 32, gen, __ATOMIC_RELAXED,
                         __HIP_MEMORY_SCOPE_AGENT);
      const int* r = rel + (w & 7) * 32;
      while (__hip_atomic_load(r, __ATOMIC_RELAXED, __HIP_MEMORY_SCOPE_AGENT) < gen)
        __builtin_amdgcn_s_sleep(1);
    }
    asm volatile("" ::: "memory");
  }
  __syncthreads();
}

// xw_t for THIS WG's 8 preact columns; h-row read DIRECTLY from global (no LDS
// staging). Thread t -> (b=t&31, s=t>>5) accumulates k-slice [64s,64s+64).
__device__ __forceinline__ float xw_compute(float* buf, const float* __restrict__ x,
                                            const float* __restrict__ PW, int tt,
                                            int b2g, int c2g) {
  const int t = threadIdx.x, b = t & 31, s = t >> 5, k0 = s * 64;
  const float* hrow = x + ((size_t)b * TSTEPS + tt) * DD + k0;
  const float* Pk = PW + k0;
  float acc[8] = {0.f,0.f,0.f,0.f,0.f,0.f,0.f,0.f};
#pragma unroll 4
  for (int kk = 0; kk < 64; kk += 4) {
    float4 hv = *(const float4*)(hrow + kk);
#pragma unroll
    for (int c = 0; c < 8; c++)
      acc[c] += dot4(hv, *(const float4*)(Pk + c * DD + kk));
  }
  __syncthreads();                       // previous buf users done
#pragma unroll
  for (int cc = 0; cc < 8; cc++) buf[(cc * 8 + s) * 32 + b] = acc[cc];
  __syncthreads();
  float sum = 0.f;
#pragma unroll
  for (int s2 = 0; s2 < 8; s2++) sum += buf[(c2g * 8 + s2) * 32 + b2g];
  return sum;
}

__global__ __launch_bounds__(BD, 1) void attn_lstm_persistent(
    const float* __restrict__ x, const float* __restrict__ ctx,
    const float* __restrict__ W, const float* __restrict__ V,
    const float* __restrict__ U, const float* __restrict__ bias,
    const float* __restrict__ Wh, const float* __restrict__ Wc,
    const float* __restrict__ batt, const float* __restrict__ wprj,
    float* __restrict__ out, float* __restrict__ ws) {
  __shared__ float buf[16384];           // 64 KB (setup staging + reductions)
  __shared__ float aux[576];
  const int w = blockIdx.x;
  const int t = threadIdx.x;
  float* hatt  = ws + OFF_HATT;
  float* att   = ws + OFF_ATT;
  float* wctxr = ws + OFF_WCTXR;
  float* Zr    = ws + OFF_ZR;
  float* packb = ws + OFF_PACK + (size_t)w * PSZ;
  int*   flags = (int*)(ws + OFF_FLAGS);
  int*   rel   = (int*)(ws + OFF_REL);
  int gen = 0;

  const int b2g = t & 31, c2g = t >> 5;          // thread->output mapping
  const int d0 = w * 2;
  const int mycol = d0 + (c2g & 1) + (c2g >> 1) * 512;
  const float bias_reg = bias[mycol];

  float xw_cur, xw_next = 0.f, hU_reg;
  float c_reg = 0.f;                              // t<64 threads own c[(t&31)][2w+(t>>5)]

  // ---------------- setup A: pack this WG's 26 weight columns k-contiguous ----------------
  {
#pragma unroll 4
    for (int i = 0; i < PCOLS * 2; i++) {         // 52 iterations x 256 threads
      int e = i * BD + t;
      int pc = e >> 9, k = e & 511;
      float v;
      if (pc < 8)       v = W[(size_t)k * KK4 + d0 + (pc & 1) + (pc >> 1) * 512];
      else if (pc < 16) { int q = pc - 8;  v = U[(size_t)k * KK4 + d0 + (q & 1) + (q >> 1) * 512]; }
      else if (pc < 24) { int q = pc - 16; v = V[(size_t)k * KK4 + d0 + (q & 1) + (q >> 1) * 512]; }
      else              v = Wh[(size_t)k * DD + d0 + (pc - 24)];
      packb[e] = v;
    }
  }
  const float* PW  = packb;
  const float* PU  = packb + 8 * DD;
  const float* PV  = packb + 16 * DD;
  const float* PWh = packb + 24 * DD;
  __syncthreads();

  // ---------------- setup B: att_ctx = context @ Wc + b_att (WG-local rows) ----------------
  {
    const int r0 = w * 16;
    for (int i = 0; i < 8; i++) {
      int idx4 = i * BD + t;
      int row = idx4 >> 7, c4 = idx4 & 127;
      ((float4*)buf)[idx4] = ((const float4*)(ctx + (size_t)(r0 + row) * DD))[c4];
    }
    __syncthreads();
    float accA[16], accB[16];
#pragma unroll
    for (int r = 0; r < 16; r++) { accA[r] = 0.f; accB[r] = 0.f; }
    const int a0 = t, a1 = t + 256;
    for (int cc = 0; cc < DD; cc++) {
      float w0 = Wc[(size_t)cc * DD + a0];
      float w1 = Wc[(size_t)cc * DD + a1];
#pragma unroll
      for (int r = 0; r < 16; r++) {
        float cv = buf[r * DD + cc];
        accA[r] += cv * w0; accB[r] += cv * w1;
      }
    }
    const float ba0 = batt[a0], ba1 = batt[a1];
    for (int r = 0; r < 16; r++) {
      att[(size_t)(r0 + r) * DD + a0] = accA[r] + ba0;   // normal: same WG reads it later
      att[(size_t)(r0 + r) * DD + a1] = accB[r] + ba1;
    }
  }
  xw_cur = xw_compute(buf, x, PW, 0, b2g, c2g);
  gsync(flags, rel, w, gen);

  // ---------------- recurrence ----------------
  for (int step = 0; step < TSTEPS; step++) {
    // ---- S1: hU (8 own cols -> reg) + hatt (2 cols, coherent store).
    //      h_{step-1} == out[:,step-1,:], read directly (fresh lines). ----
    {
      const int b = t & 31, s = t >> 5, k0 = s * 64;
      float acc[10];
#pragma unroll
      for (int i = 0; i < 10; i++) acc[i] = 0.f;
      if (step > 0) {
        const float* hrow = out + (size_t)b * (TSTEPS * DD) + (size_t)(step - 1) * DD + k0;
        const float* Pk   = PU + k0;
        const float* Pwh  = PWh + k0;
#pragma unroll 4
        for (int kk = 0; kk < 64; kk += 4) {
          float4 hv = *(const float4*)(hrow + kk);
#pragma unroll
          for (int c = 0; c < 8; c++)
            acc[c] += dot4(hv, *(const float4*)(Pk + c * DD + kk));
          acc[8] += dot4(hv, *(const float4*)(Pwh + kk));
          acc[9] += dot4(hv, *(const float4*)(Pwh + DD + kk));
        }
      }
#pragma unroll
      for (int cc = 0; cc < 10; cc++) buf[(cc * 8 + s) * 32 + b] = acc[cc];
      __syncthreads();
      float hu = 0.f;
#pragma unroll
      for (int s2 = 0; s2 < 8; s2++) hu += buf[(c2g * 8 + s2) * 32 + b2g];
      hU_reg = hu;
      if (t < 64) {
        const int b3 = t & 31, j = t >> 5;
        float sum = 0.f;
#pragma unroll
        for (int s2 = 0; s2 < 8; s2++) sum += buf[((8 + j) * 8 + s2) * 32 + b3];
        cstore(hatt + (size_t)b3 * DD + d0 + j, sum);
      }
    }
    gsync(flags, rel, w, gen);

    // ---- S2: attention scores + unnormalized wctx into ring slot; prefetch xw[t+1] ----
    {
      float* wslot = wctxr + (size_t)step * 16384;
      float* zslot = Zr + (size_t)step * 64;
      const int b = w >> 3, l0 = (w & 7) * 16;
      // stage hatt row b (coherent) into aux[0..512)
      aux[t]       = cload(hatt + (size_t)b * DD + t);
      aux[256 + t] = cload(hatt + (size_t)b * DD + 256 + t);
      __syncthreads();
      const int l = t >> 4, u = t & 15;
      const float* ar = att + (size_t)(b * LC + l0 + l) * DD;
      float p = 0.f;
#pragma unroll
      for (int j = 0; j < 8; j++) {
        int a4 = j * 16 + u;
        float4 av = ((const float4*)ar)[a4];
        float4 wv = ((const float4*)wprj)[a4];
        float hx = aux[a4*4], hy = aux[a4*4+1], hz = aux[a4*4+2], hw = aux[a4*4+3];
        p += ftanh(av.x + hx) * wv.x + ftanh(av.y + hy) * wv.y
           + ftanh(av.z + hz) * wv.z + ftanh(av.w + hw) * wv.w;
      }
      p += __shfl_xor(p, 8); p += __shfl_xor(p, 4);
      p += __shfl_xor(p, 2); p += __shfl_xor(p, 1);
      if (u == 0) {
        float uv = __expf(p);
        aux[512 + l] = uv;
        atomicAdd(&zslot[b], uv);        // device-scope -> MALL
      }
      __syncthreads();
      float s0 = 0.f, s1 = 0.f;
      const float* cr = ctx + (size_t)(b * LC + l0) * DD;
#pragma unroll 4
      for (int l2 = 0; l2 < 16; l2++) {
        float uv = aux[512 + l2];
        s0 += uv * cr[l2 * DD + t];
        s1 += uv * cr[l2 * DD + t + 256];
      }
      atomicAdd(&wslot[(size_t)b * DD + t], s0);
      atomicAdd(&wslot[(size_t)b * DD + t + 256], s1);
      if (step + 1 < TSTEPS) xw_next = xw_compute(buf, x, PW, step + 1, b2g, c2g);
    }
    gsync(flags, rel, w, gen);

    // ---- S3: preact = xw + hU + wctx@V + bias; gates; h/c update.
    //      wctx ring slot read directly (fresh lines). ----
    {
      const int b = t & 31, s = t >> 5, k0 = s * 64;
      if (t < 32) aux[t] = Zr[(size_t)step * 64 + t];
      const float* wrow = wctxr + (size_t)step * 16384 + (size_t)b * DD + k0;
      const float* Pk   = PV + k0;
      float acc[8] = {0.f,0.f,0.f,0.f,0.f,0.f,0.f,0.f};
#pragma unroll 4
      for (int kk = 0; kk < 64; kk += 4) {
        float4 hv = *(const float4*)(wrow + kk);
#pragma unroll
        for (int c = 0; c < 8; c++)
          acc[c] += dot4(hv, *(const float4*)(Pk + c * DD + kk));
      }
      __syncthreads();                   // aux (Z) visible
      const float rz = rcp_fast(aux[b]);
#pragma unroll
      for (int cc = 0; cc < 8; cc++) buf[(cc * 8 + s) * 32 + b] = acc[cc] * rz;
      __syncthreads();
      {
        float sum = 0.f;
#pragma unroll
        for (int s2 = 0; s2 < 8; s2++) sum += buf[(c2g * 8 + s2) * 32 + b2g];
        sum += xw_cur + hU_reg + bias_reg;
        buf[2048 + c2g * 32 + b2g] = sum;        // disjoint from partials region
      }
      __syncthreads();
      if (t < 64) {
        const int b3 = t & 31, dd = t >> 5;
        const int d = d0 + dd;
        float pi = buf[2048 + (0 + dd) * 32 + b3];
        float pf = buf[2048 + (2 + dd) * 32 + b3];
        float po = buf[2048 + (4 + dd) * 32 + b3];
        float pg = buf[2048 + (6 + dd) * 32 + b3];
        float ig = fsig(pi), fg = fsig(pf), og = fsig(po), gg = ftanh(pg);
        float cn = fg * c_reg + ig * gg;
        c_reg = cn;
        float hn = og * ftanh(cn);
        // h_t == out[:,t,:]; sc1 store -> MALL so next step's S1 loads see it
        cstore(out + (size_t)b3 * (TSTEPS * DD) + (size_t)step * DD + d, hn);
      }
      xw_cur = xw_next;
    }
    gsync(flags, rel, w, gen);
  }
}

extern "C" void kernel_launch(void* const* d_in, const int* in_sizes, int n_in,
                              void* d_out, int out_size, void* d_ws, size_t ws_size,
                              hipStream_t stream) {
  (void)in_sizes; (void)n_in; (void)out_size; (void)ws_size;
  const float* x    = (const float*)d_in[0];
  const float* ctx  = (const float*)d_in[1];
  const float* W    = (const float*)d_in[2];
  const float* V    = (const float*)d_in[3];
  const float* U    = (const float*)d_in[4];
  const float* b    = (const float*)d_in[5];
  const float* Wh   = (const float*)d_in[6];
  const float* Wc   = (const float*)d_in[7];
  const float* batt = (const float*)d_in[8];
  const float* wprj = (const float*)d_in[9];

  // zero the wctx/Z rings (accumulated by atomics) and barrier flags/release
  hipMemsetAsync((char*)d_ws + OFF_WCTXR * sizeof(float), 0,
                 (4194304 + 16384) * sizeof(float), stream);
  hipMemsetAsync((char*)d_ws + OFF_FLAGS * sizeof(float), 0,
                 (8192 + 256) * sizeof(int), stream);

  hipLaunchKernelGGL(attn_lstm_persistent, dim3(GD), dim3(BD), 0, stream,
                     x, ctx, W, V, U, b, Wh, Wc, batt, wprj,
                     (float*)d_out, (float*)d_ws);
}